// Round 4
// baseline (135.762 us; speedup 1.0000x reference)
//
#include <hip/hip_runtime.h>
#include <math.h>

#define NN 50000
#define NE 800000
#define NH 4
#define HD 32
#define FD 128      // NH*HD == IN_DIM
#define NTILE 3125  // 50000 / 16 exactly
#define GEMM_BLOCKS 512                 // grid-stride, 8 waves/block, 2 blocks/CU
#define ROWS_BLOCKS ((NE + 511) / 512)  // 1563
#define NPB 16      // nodes per aggregate block (50000/16 = 3125 blocks exactly)
#define NPW 4       // nodes per wave
#define CAP 1008    // edges per LDS chunk; wS+sS+rS = 20.2 KB -> 8 blocks/CU

typedef __attribute__((ext_vector_type(8))) short short8;
typedef __attribute__((ext_vector_type(4))) float floatx4;

__device__ __forceinline__ unsigned short f2bf(float f) {
    union { float f; unsigned u; } v; v.f = f;
    unsigned u = v.u;
    return (unsigned short)((u + 0x7FFFu + ((u >> 16) & 1u)) >> 16);
}
__device__ __forceinline__ float bfu(unsigned short u) {
    union { unsigned u; float f; } v; v.u = (unsigned)u << 16; return v.f;
}
__device__ __forceinline__ float bf_lo(unsigned u) {
    union { unsigned u; float f; } v; v.u = u << 16; return v.f;
}
__device__ __forceinline__ float bf_hi(unsigned u) {
    union { unsigned u; float f; } v; v.u = u & 0xFFFF0000u; return v.f;
}

// ---------------------------------------------------------------------------
// Kernel 1: projection via bf16 MFMA. el/er computed by 4 EXTRA MFMAs against
// a per-block precomputed Wa = W^T [a_l | a_r] tile (el = x.(W^T a_l)) — no
// cross-lane shuffle reduce. CSR row-offset builder fused as trailing blocks.
// (unchanged from round 3)
// ---------------------------------------------------------------------------
__global__ __launch_bounds__(512) void k_gemm_rows(const float* __restrict__ x,
                                                   const float* __restrict__ W,
                                                   const float* __restrict__ al,
                                                   const float* __restrict__ ar,
                                                   const int* __restrict__ dst,
                                                   unsigned short* __restrict__ feat_bf,
                                                   float* __restrict__ el,
                                                   float* __restrict__ er,
                                                   int* __restrict__ rows) {
    const int tid = threadIdx.x;

    if (blockIdx.x >= GEMM_BLOCKS) {
        // ---- CSR row offsets from sorted dst ----
        int e = (blockIdx.x - GEMM_BLOCKS) * 512 + tid;
        if (e < NE) {
            int dj = dst[e];
            if (e == 0) {
                for (int n = 0; n <= dj; ++n) rows[n] = 0;
            } else {
                int prev = dst[e - 1];
                for (int n = prev + 1; n <= dj; ++n) rows[n] = e;
            }
            if (e == NE - 1) {
                for (int n = dj + 1; n <= NN; ++n) rows[n] = NE;
            }
        }
        return;
    }

    __shared__ unsigned short Wl[FD * 136];    // Wl[c][k], row stride 136 bf16
    __shared__ unsigned short WaL[16 * 136];   // Wa[c][k]: c<8 = W^T[a_l|a_r], c>=8 zero
    __shared__ float aS[2 * FD];               // al | ar

    for (int p = tid; p < FD * 64; p += 512) {
        int c = p >> 6, k2 = (p & 63) * 2;
        float2 wv = *(const float2*)&W[c * FD + k2];
        *(unsigned*)&Wl[c * 136 + k2] =
            (unsigned)f2bf(wv.x) | ((unsigned)f2bf(wv.y) << 16);
    }
    if (tid < FD) aS[tid] = al[tid];
    else if (tid < 2 * FD) aS[tid] = ar[tid - FD];
    __syncthreads();

    // Wa[c][k] = sum_d a[c][d] * W[32h+d][k], h = c&3; one-time per block.
    for (int p = tid; p < 16 * FD; p += 512) {
        int c = p >> 7, k = p & 127;
        float v = 0.f;
        if (c < 8) {
            int h = c & 3;
            const float* av = &aS[(c >> 2) * FD + h * HD];
            const unsigned short* wl = &Wl[h * HD * 136 + k];
            #pragma unroll 8
            for (int d = 0; d < HD; ++d) v += bfu(wl[d * 136]) * av[d];
        }
        WaL[c * 136 + k] = f2bf(v);
    }
    __syncthreads();

    const int wv_id = tid >> 6, lane = tid & 63;
    const int col = lane & 15, quad = lane >> 4;

    for (int tile = blockIdx.x * 8 + wv_id; tile < NTILE; tile += GEMM_BLOCKS * 8) {
        const int n0 = tile * 16;

        short8 afrag[4];
        const float* xrow = x + (size_t)(n0 + col) * FD;
        #pragma unroll
        for (int s = 0; s < 4; ++s) {
            float4 u0 = *(const float4*)&xrow[s * 32 + quad * 8];
            float4 u1 = *(const float4*)&xrow[s * 32 + quad * 8 + 4];
            short8 a;
            a[0] = (short)f2bf(u0.x); a[1] = (short)f2bf(u0.y);
            a[2] = (short)f2bf(u0.z); a[3] = (short)f2bf(u0.w);
            a[4] = (short)f2bf(u1.x); a[5] = (short)f2bf(u1.y);
            a[6] = (short)f2bf(u1.z); a[7] = (short)f2bf(u1.w);
            afrag[s] = a;
        }

        floatx4 acc[8], acce;
        #pragma unroll
        for (int ct = 0; ct < 8; ++ct) acc[ct] = (floatx4){0.f, 0.f, 0.f, 0.f};
        acce = (floatx4){0.f, 0.f, 0.f, 0.f};

        #pragma unroll
        for (int ct = 0; ct < 8; ++ct) {
            #pragma unroll
            for (int s = 0; s < 4; ++s) {
                short8 b = *(const short8*)&Wl[(ct * 16 + col) * 136 + s * 32 + quad * 8];
                acc[ct] = __builtin_amdgcn_mfma_f32_16x16x32_bf16(afrag[s], b, acc[ct], 0, 0, 0);
            }
        }
        #pragma unroll
        for (int s = 0; s < 4; ++s) {
            short8 b = *(const short8*)&WaL[col * 136 + s * 32 + quad * 8];
            acce = __builtin_amdgcn_mfma_f32_16x16x32_bf16(afrag[s], b, acce, 0, 0, 0);
        }

        // feat store (C/D: col = lane&15, row = quad*4 + reg)
        #pragma unroll
        for (int ct = 0; ct < 8; ++ct) {
            #pragma unroll
            for (int r = 0; r < 4; ++r) {
                feat_bf[(size_t)(n0 + quad * 4 + r) * FD + ct * 16 + col] = f2bf(acc[ct][r]);
            }
        }
        // el/er store: acce col 0..3 = el heads, col 4..7 = er heads
        #pragma unroll
        for (int r = 0; r < 4; ++r) {
            int n = n0 + quad * 4 + r;
            if (col < 4)      el[n * NH + col]     = acce[r];
            else if (col < 8) er[n * NH + col - 4] = acce[r];
        }
    }
}

// ---------------------------------------------------------------------------
// Kernel 2: aggregation, 16 nodes per block (4 per wave, serial), LDS weights
// and src indices. Phase 1 covers ~256 edges with ALL 256 threads active
// (4x utilization vs round 3 on the dependent src->el gather chain); blocks
// 12500 -> 3125 (barriers and per-block fixed cost /4).
// A wave's current node keeps its accumulator across chunk boundaries (at
// most one mid-flight node per wave), so CAP chunking stays fully correct.
// ---------------------------------------------------------------------------
__global__ __launch_bounds__(256) void k_aggregate(const unsigned short* __restrict__ feat_bf,
                                                   const float* __restrict__ el,
                                                   const float* __restrict__ er,
                                                   const int* __restrict__ src,
                                                   const int* __restrict__ dst,
                                                   const int* __restrict__ rows,
                                                   float* __restrict__ out) {
    __shared__ float wS[CAP * NH];   // 15.75 KB
    __shared__ int   sS[CAP];        // 3.94 KB
    __shared__ int   rS[NPB + 1];    // 68 B  (total 20.2 KB -> 8 blocks/CU)
    const int tid = threadIdx.x;
    const int wave = tid >> 6;
    const int lane = tid & 63;
    const int n0 = blockIdx.x * NPB;     // NN % NPB == 0

    if (tid <= NPB) rS[tid] = rows[n0 + tid];
    __syncthreads();

    const int s0 = rS[0];
    const int tE = rS[NPB];

    const int q  = lane >> 4;        // edge slot 0..3
    const int lp = lane & 15;        // dim slot: dims 8*lp .. 8*lp+7
    const int h  = lp >> 2;          // head of those dims
    const int dimoff = 8 * lp;

    // this wave's node row bounds (wave-uniform LDS broadcasts)
    int gsv[NPW + 1];
    #pragma unroll
    for (int i = 0; i <= NPW; ++i) gsv[i] = rS[wave * NPW + i];

    float acc[8] = {0.f, 0.f, 0.f, 0.f, 0.f, 0.f, 0.f, 0.f};
    float den = 0.f;
    int ni = 0;                      // current local node, wave-uniform

    for (int c0 = s0; c0 < tE; c0 += CAP) {
        const int c1 = min(c0 + CAP, tE);

        // ---- phase 1: per-edge weights + src into LDS (all threads) ----
        for (int e = c0 + tid; e < c1; e += 256) {
            int sj = src[e], dj = dst[e];
            sS[e - c0] = sj;
            float4 l4 = *(const float4*)&el[sj * NH];
            float4 r4 = *(const float4*)&er[dj * NH];
            float4 w; float lg;
            lg = l4.x + r4.x; w.x = __expf(fmaxf(lg, 0.2f * lg));
            lg = l4.y + r4.y; w.y = __expf(fmaxf(lg, 0.2f * lg));
            lg = l4.z + r4.z; w.z = __expf(fmaxf(lg, 0.2f * lg));
            lg = l4.w + r4.w; w.w = __expf(fmaxf(lg, 0.2f * lg));
            *(float4*)&wS[(e - c0) * NH] = w;
        }
        __syncthreads();

        // ---- phase 2: this wave's nodes, serial ----
        while (ni < NPW) {
            const int gs = gsv[ni], ge = gsv[ni + 1];
            const int sb = max(gs, c0), tb = min(ge, c1);
            for (int e = sb; e < tb; e += 16) {
                const int base = e + 4 * q;
                float wv4[4];
                int   sj4[4];
                uint4 uvv[4];
                #pragma unroll
                for (int u = 0; u < 4; ++u) {
                    int ei = base + u;
                    bool v = ei < tb;                  // ei >= sb guaranteed
                    int ii = v ? (ei - c0) : 0;        // clamped: LDS-safe
                    sj4[u] = sS[ii];
                    wv4[u] = v ? wS[ii * NH + h] : 0.f;
                    if (v) uvv[u] = *(const uint4*)&feat_bf[(size_t)sj4[u] * FD + dimoff];
                }
                #pragma unroll
                for (int u = 0; u < 4; ++u) {
                    int ei = base + u;
                    if (ei < tb) {
                        float w = wv4[u];
                        uint4 uv = uvv[u];
                        acc[0] += w * bf_lo(uv.x); acc[1] += w * bf_hi(uv.x);
                        acc[2] += w * bf_lo(uv.y); acc[3] += w * bf_hi(uv.y);
                        acc[4] += w * bf_lo(uv.z); acc[5] += w * bf_hi(uv.z);
                        acc[6] += w * bf_lo(uv.w); acc[7] += w * bf_hi(uv.w);
                        den += w;
                    }
                }
            }
            if (ge > c1) break;      // node continues in next chunk: keep acc

            // finalize node: combine the 4 edge-groups (lane bits 4,5)
            #pragma unroll
            for (int m = 16; m < 64; m <<= 1) {
                #pragma unroll
                for (int j = 0; j < 8; ++j) acc[j] += __shfl_xor(acc[j], m);
                den += __shfl_xor(den, m);
            }
            if (q == 0) {
                const float rden = (den > 0.f) ? 1.f / den : 0.f;
                float* op = out + (size_t)(n0 + wave * NPW + ni) * FD + dimoff;
                *(float4*)op       = make_float4(acc[0] * rden, acc[1] * rden, acc[2] * rden, acc[3] * rden);
                *(float4*)(op + 4) = make_float4(acc[4] * rden, acc[5] * rden, acc[6] * rden, acc[7] * rden);
            }
            #pragma unroll
            for (int j = 0; j < 8; ++j) acc[j] = 0.f;
            den = 0.f;
            ++ni;
        }
        __syncthreads();             // before next chunk overwrites wS/sS
    }
}

// ---------------------------------------------------------------------------
extern "C" void kernel_launch(void* const* d_in, const int* in_sizes, int n_in,
                              void* d_out, int out_size, void* d_ws, size_t ws_size,
                              hipStream_t stream) {
    const float* x  = (const float*)d_in[0];
    const float* W  = (const float*)d_in[1];
    const float* al = (const float*)d_in[2];
    const float* ar = (const float*)d_in[3];
    const int* src  = (const int*)d_in[4];
    const int* dst  = (const int*)d_in[5];
    float* out = (float*)d_out;

    // ws: feat_bf[NN*FD] ushort | el[NN*NH] f32 | er[NN*NH] f32 | rows[NN+1]
    unsigned short* feat_bf = (unsigned short*)d_ws;
    float* el = (float*)(feat_bf + (size_t)NN * FD);
    float* er = el + (size_t)NN * NH;
    int*   rows = (int*)(er + (size_t)NN * NH);

    k_gemm_rows<<<GEMM_BLOCKS + ROWS_BLOCKS, 512, 0, stream>>>(x, W, al, ar, dst,
                                                               feat_bf, el, er, rows);
    k_aggregate<<<NN / NPB, 256, 0, stream>>>(feat_bf, el, er, src, dst, rows, out);
}